// Round 7
// baseline (677.004 us; speedup 1.0000x reference)
//
#include <hip/hip_runtime.h>
#include <math.h>

#define VOCAB 30000
#define EMB   100
#define HID   128
#define BATCH 1024
#define SEQ   512

typedef float f32x4 __attribute__((ext_vector_type(4)));

// Kernel A: EWx[v][j] = sum_e E[v][e]*Wx[e][j] + b[j]   (folds bias in)
__global__ __launch_bounds__(256) void ewx_kernel(
    const float* __restrict__ E, const float* __restrict__ Wx,
    const float* __restrict__ bias, float* __restrict__ EWx)
{
    __shared__ float Es[64][EMB];     // 25.6 KB
    __shared__ float Wxs[EMB][HID];   // 51.2 KB
    const int tid = threadIdx.x;
    const int v0 = blockIdx.x * 64;
    const int nv = min(64, VOCAB - v0);

    {
        const float4* s4 = (const float4*)Wx;
        float4* d4 = (float4*)(&Wxs[0][0]);
        for (int i = tid; i < (EMB * HID) / 4; i += 256) d4[i] = s4[i];
    }
    {
        const float* src = E + (size_t)v0 * EMB;
        float* dst = &Es[0][0];
        const int n  = nv * EMB;
        const int n4 = n >> 2;
        const float4* s4 = (const float4*)src;
        float4* d4 = (float4*)dst;
        for (int i = tid; i < n4; i += 256) d4[i] = s4[i];
        for (int i = (n4 << 2) + tid; i < n; i += 256) dst[i] = src[i];
    }
    __syncthreads();

    const int j  = tid & 127;
    const int vh = tid >> 7;
    float acc[32];
#pragma unroll
    for (int m = 0; m < 32; ++m) acc[m] = 0.f;

    for (int k4 = 0; k4 < EMB; k4 += 4) {
        const float w0 = Wxs[k4 + 0][j];
        const float w1 = Wxs[k4 + 1][j];
        const float w2 = Wxs[k4 + 2][j];
        const float w3 = Wxs[k4 + 3][j];
#pragma unroll
        for (int m = 0; m < 32; ++m) {
            const float4 e = *(const float4*)&Es[vh + 2 * m][k4];
            acc[m] = fmaf(e.x, w0, acc[m]);
            acc[m] = fmaf(e.y, w1, acc[m]);
            acc[m] = fmaf(e.z, w2, acc[m]);
            acc[m] = fmaf(e.w, w3, acc[m]);
        }
    }
    const float bj = bias[j];
#pragma unroll
    for (int m = 0; m < 32; ++m) {
        const int v = vh + 2 * m;
        if (v < nv)
            EWx[(size_t)(v0 + v) * HID + j] = acc[m] + bj;
    }
}

// Kernel B: sequential recurrence, 4 batch rows per block, 512 threads.
// Thread = (kqh = tid>>7 in 0..3, cg = (tid>>2)&31, kql = tid&3);
// k-slice ks = 4*kqh + kql covers k in [8ks, 8ks+8); cols 4cg..4cg+3.
// Weights/thread: 8k x 4c = 32 scalars (HALF of rounds 2-6 — those all
// failed to keep 64 resident: remat at cap (r2/r5), scratch (r3/r4),
// working-set starvation (r6: VGPR=88 = 64 pinned + 24 spare, stalls).
// 32 W + 16 acc + temps ~= 80 VGPR: fits without allocator heroics.
// FMA/thread unchanged (32 w x 4 rows = 128).
// k-reduce: 16 slices = 2 lane-local DPP folds (shfl_xor 1,2 within the
// quad) + 4-way LDS reduce through part[4][4][HID]. 2 barriers/step.
__global__ __launch_bounds__(512)
__attribute__((amdgpu_waves_per_eu(2, 2)))
void rnn_kernel(
    const int* __restrict__ X, const float* __restrict__ EWx,
    const float* __restrict__ Wh, const float* __restrict__ Wd,
    const float* __restrict__ bd, float* __restrict__ out)
{
    __shared__ __align__(16) float hbuf[2][4][HID];  // 4 KB, double-buffered
    __shared__ __align__(16) float part[4][4][HID];  // 8 KB partials
    __shared__ int idx[4][SEQ];                      // 8 KB token indices

    const int tid = threadIdx.x;
    const int kql = tid & 3;           // k-low (folded by DPP shuffles)
    const int cg  = (tid >> 2) & 31;   // column group: cols 4cg..4cg+3
    const int kqh = tid >> 7;          // k-high (folded through LDS)
    const int ks  = kqh * 4 + kql;     // k-slice: k in [8ks, 8ks+8)
    const int b0  = blockIdx.x * 4;

    for (int i = tid; i < 4 * SEQ; i += 512)
        idx[i >> 9][i & 511] = X[(size_t)(b0 + (i >> 9)) * SEQ + (i & 511)];

    // 32 weights in named scalars: Wh[8ks+kk][4cg..4cg+3], kk = 0..7
#define DECLW(kk) float W##kk##_0, W##kk##_1, W##kk##_2, W##kk##_3;
    DECLW(0) DECLW(1) DECLW(2) DECLW(3) DECLW(4) DECLW(5) DECLW(6) DECLW(7)
#undef DECLW
#define LOADW(kk) { const f32x4 w_ = *reinterpret_cast<const f32x4*>(      \
        &Wh[(size_t)(8 * ks + kk) * HID + 4 * cg]);                        \
        W##kk##_0 = w_.x; W##kk##_1 = w_.y;                                \
        W##kk##_2 = w_.z; W##kk##_3 = w_.w; }
    LOADW(0) LOADW(1) LOADW(2) LOADW(3) LOADW(4) LOADW(5) LOADW(6) LOADW(7)
#undef LOADW

    (&hbuf[0][0][0])[tid] = 0.f;       // h0 = 0 ([0] is 4*128 = 512 floats)
    __syncthreads();

    const int rf = tid >> 7;           // row this thread finalizes (=kqh)
    const int cf = tid & 127;          // column this thread finalizes

    int cur = 0;
    for (int t = 0; t < SEQ; ++t) {
        // issue xp gather early; consumed at finalize (hidden under FMAs)
        const int   tok = idx[rf][t];
        const float xp  = EWx[(size_t)tok * HID + cf];

        // h fragments: 2 x b128 per row; per-inst 4 addrs 32B apart ->
        // distinct bank groups, conflict-free broadcast.
        const f32x4* h0 = (const f32x4*)&hbuf[cur][0][8 * ks];
        const f32x4* h1 = (const f32x4*)&hbuf[cur][1][8 * ks];
        const f32x4* h2 = (const f32x4*)&hbuf[cur][2][8 * ks];
        const f32x4* h3 = (const f32x4*)&hbuf[cur][3][8 * ks];

        float A0_0=0.f,A0_1=0.f,A0_2=0.f,A0_3=0.f;
        float A1_0=0.f,A1_1=0.f,A1_2=0.f,A1_3=0.f;
        float A2_0=0.f,A2_1=0.f,A2_2=0.f,A2_3=0.f;
        float A3_0=0.f,A3_1=0.f,A3_2=0.f,A3_3=0.f;

#define FMA16(kk, v0, v1, v2, v3)                                          \
        A0_0=fmaf(v0,W##kk##_0,A0_0); A0_1=fmaf(v0,W##kk##_1,A0_1);        \
        A0_2=fmaf(v0,W##kk##_2,A0_2); A0_3=fmaf(v0,W##kk##_3,A0_3);        \
        A1_0=fmaf(v1,W##kk##_0,A1_0); A1_1=fmaf(v1,W##kk##_1,A1_1);        \
        A1_2=fmaf(v1,W##kk##_2,A1_2); A1_3=fmaf(v1,W##kk##_3,A1_3);        \
        A2_0=fmaf(v2,W##kk##_0,A2_0); A2_1=fmaf(v2,W##kk##_1,A2_1);        \
        A2_2=fmaf(v2,W##kk##_2,A2_2); A2_3=fmaf(v2,W##kk##_3,A2_3);        \
        A3_0=fmaf(v3,W##kk##_0,A3_0); A3_1=fmaf(v3,W##kk##_1,A3_1);        \
        A3_2=fmaf(v3,W##kk##_2,A3_2); A3_3=fmaf(v3,W##kk##_3,A3_3);

        { const f32x4 u0 = h0[0], u1 = h1[0], u2 = h2[0], u3 = h3[0];
          FMA16(0, u0.x, u1.x, u2.x, u3.x)
          FMA16(1, u0.y, u1.y, u2.y, u3.y)
          FMA16(2, u0.z, u1.z, u2.z, u3.z)
          FMA16(3, u0.w, u1.w, u2.w, u3.w) }
        { const f32x4 u0 = h0[1], u1 = h1[1], u2 = h2[1], u3 = h3[1];
          FMA16(4, u0.x, u1.x, u2.x, u3.x)
          FMA16(5, u0.y, u1.y, u2.y, u3.y)
          FMA16(6, u0.z, u1.z, u2.z, u3.z)
          FMA16(7, u0.w, u1.w, u2.w, u3.w) }
#undef FMA16

        // fold k-low: quads differ only in kql -> xor 1,2 are quad_perm DPP
#define FOLD(x) x += __shfl_xor(x, 1, 64); x += __shfl_xor(x, 2, 64);
        FOLD(A0_0) FOLD(A0_1) FOLD(A0_2) FOLD(A0_3)
        FOLD(A1_0) FOLD(A1_1) FOLD(A1_2) FOLD(A1_3)
        FOLD(A2_0) FOLD(A2_1) FOLD(A2_2) FOLD(A2_3)
        FOLD(A3_0) FOLD(A3_1) FOLD(A3_2) FOLD(A3_3)
#undef FOLD

        if (kql == 0) {                // one writer per quad, b128 each row
            f32x4 p;
            p.x=A0_0; p.y=A0_1; p.z=A0_2; p.w=A0_3;
            *reinterpret_cast<f32x4*>(&part[0][kqh][4 * cg]) = p;
            p.x=A1_0; p.y=A1_1; p.z=A1_2; p.w=A1_3;
            *reinterpret_cast<f32x4*>(&part[1][kqh][4 * cg]) = p;
            p.x=A2_0; p.y=A2_1; p.z=A2_2; p.w=A2_3;
            *reinterpret_cast<f32x4*>(&part[2][kqh][4 * cg]) = p;
            p.x=A3_0; p.y=A3_1; p.z=A3_2; p.w=A3_3;
            *reinterpret_cast<f32x4*>(&part[3][kqh][4 * cg]) = p;
        }
        __syncthreads();

        // finalize (rf, cf): 4-way reduce (stride-1 b32 reads) + xp + tanh
        const float s = xp + part[rf][0][cf] + part[rf][1][cf]
                           + part[rf][2][cf] + part[rf][3][cf];
        const float x  = fminf(fmaxf(s, -9.f), 9.f);  // tanh saturates past 9
        const float e2 = __expf(2.f * x);
        hbuf[cur ^ 1][rf][cf] = __fdividef(e2 - 1.f, e2 + 1.f);
        __syncthreads();
        cur ^= 1;
    }

    // head: out[b] = sigmoid(h . Wd + bd)
    if (tid < 256) {
        const int rr   = tid >> 6;
        const int lane = tid & 63;
        const float* hb = hbuf[cur][rr];
        float v = hb[lane] * Wd[lane] + hb[lane + 64] * Wd[lane + 64];
#pragma unroll
        for (int off = 32; off > 0; off >>= 1)
            v += __shfl_down(v, off, 64);
        if (lane == 0)
            out[b0 + rr] = 1.0f / (1.0f + expf(-(v + bd[0])));
    }
}

extern "C" void kernel_launch(void* const* d_in, const int* in_sizes, int n_in,
                              void* d_out, int out_size, void* d_ws, size_t ws_size,
                              hipStream_t stream)
{
    const int*   X  = (const int*)d_in[0];
    const float* E  = (const float*)d_in[1];
    const float* Wx = (const float*)d_in[2];
    const float* Wh = (const float*)d_in[3];
    const float* b  = (const float*)d_in[4];
    const float* Wd = (const float*)d_in[5];
    const float* bd = (const float*)d_in[6];
    float* out = (float*)d_out;
    float* EWx = (float*)d_ws;   // 30000*128*4 = 15.36 MB scratch

    ewx_kernel<<<dim3((VOCAB + 63) / 64), dim3(256), 0, stream>>>(E, Wx, b, EWx);
    rnn_kernel<<<dim3(BATCH / 4), dim3(512), 0, stream>>>(X, EWx, Wh, Wd, bd, out);
}

// Round 8
// 661.461 us; speedup vs baseline: 1.0235x; 1.0235x over previous
//
#include <hip/hip_runtime.h>
#include <math.h>

#define VOCAB 30000
#define EMB   100
#define HID   128
#define BATCH 1024
#define SEQ   512

typedef float f32x4 __attribute__((ext_vector_type(4)));

// Kernel A: EWx[v][j] = sum_e E[v][e]*Wx[e][j] + b[j]   (folds bias in)
__global__ __launch_bounds__(256) void ewx_kernel(
    const float* __restrict__ E, const float* __restrict__ Wx,
    const float* __restrict__ bias, float* __restrict__ EWx)
{
    __shared__ float Es[64][EMB];     // 25.6 KB
    __shared__ float Wxs[EMB][HID];   // 51.2 KB
    const int tid = threadIdx.x;
    const int v0 = blockIdx.x * 64;
    const int nv = min(64, VOCAB - v0);

    {
        const float4* s4 = (const float4*)Wx;
        float4* d4 = (float4*)(&Wxs[0][0]);
        for (int i = tid; i < (EMB * HID) / 4; i += 256) d4[i] = s4[i];
    }
    {
        const float* src = E + (size_t)v0 * EMB;
        float* dst = &Es[0][0];
        const int n  = nv * EMB;
        const int n4 = n >> 2;
        const float4* s4 = (const float4*)src;
        float4* d4 = (float4*)dst;
        for (int i = tid; i < n4; i += 256) d4[i] = s4[i];
        for (int i = (n4 << 2) + tid; i < n; i += 256) dst[i] = src[i];
    }
    __syncthreads();

    const int j  = tid & 127;
    const int vh = tid >> 7;
    float acc[32];
#pragma unroll
    for (int m = 0; m < 32; ++m) acc[m] = 0.f;

    for (int k4 = 0; k4 < EMB; k4 += 4) {
        const float w0 = Wxs[k4 + 0][j];
        const float w1 = Wxs[k4 + 1][j];
        const float w2 = Wxs[k4 + 2][j];
        const float w3 = Wxs[k4 + 3][j];
#pragma unroll
        for (int m = 0; m < 32; ++m) {
            const float4 e = *(const float4*)&Es[vh + 2 * m][k4];
            acc[m] = fmaf(e.x, w0, acc[m]);
            acc[m] = fmaf(e.y, w1, acc[m]);
            acc[m] = fmaf(e.z, w2, acc[m]);
            acc[m] = fmaf(e.w, w3, acc[m]);
        }
    }
    const float bj = bias[j];
#pragma unroll
    for (int m = 0; m < 32; ++m) {
        const int v = vh + 2 * m;
        if (v < nv)
            EWx[(size_t)(v0 + v) * HID + j] = acc[m] + bj;
    }
}

// Kernel B: sequential recurrence. 512 threads, 2 batch rows/block,
// grid = 512 blocks = 2 blocks/CU (r7 proved 1 block/CU exposes barrier
// latency: VALU 30%). 4 waves/SIMD declared via waves_per_eu(4,4) so the
// RA doesn't target LDS-implied occupancy and remat the weights (r2-r5).
// Thread = (kqh = tid>>7, cg = (tid>>2)&31, kql = tid&3), ks = 4kqh+kql:
// owns Wh[8ks..8ks+8)[4cg..4cg+3] = 32 weights (r7-proven resident) for
// BOTH rows -> 64 FMA/thread/step.
// h-reads: per wave 4 distinct addrs, 32B apart in a 128B window ->
// conflict-free broadcast (r7 measured BANK_CONFLICT=0). Only 64B/thread
// -> LDS pipe ~1/4 of the r2 structure (its real bottleneck).
// k-reduce: 16 slices = 2 shfl_xor folds (kql, lane bits 0-1) + 4-way
// LDS reduce over kqh through part[2][4][HID]. 2 barriers/step.
__global__ __launch_bounds__(512)
__attribute__((amdgpu_waves_per_eu(4, 4)))
void rnn_kernel(
    const int* __restrict__ X, const float* __restrict__ EWx,
    const float* __restrict__ Wh, const float* __restrict__ Wd,
    const float* __restrict__ bd, float* __restrict__ out)
{
    __shared__ __align__(16) float hbuf[2][2][HID];  // 2 KB, double-buffered
    __shared__ __align__(16) float part[2][4][HID];  // 4 KB partials
    __shared__ int idx[2][SEQ];                      // 4 KB token indices

    const int tid = threadIdx.x;
    const int kql = tid & 3;           // k-low (folded by shuffles)
    const int cg  = (tid >> 2) & 31;   // column group: cols 4cg..4cg+3
    const int kqh = (tid >> 7) & 3;    // k-high (folded through LDS)
    const int ks  = kqh * 4 + kql;     // k-slice: k in [8ks, 8ks+8)
    const int b0  = blockIdx.x * 2;

    for (int i = tid; i < 2 * SEQ; i += 512)
        idx[i >> 9][i & 511] = X[(size_t)(b0 + (i >> 9)) * SEQ + (i & 511)];

    // 32 weights in named scalars: Wh[8ks+kk][4cg..4cg+3], kk = 0..7
#define DECLW(kk) float W##kk##_0, W##kk##_1, W##kk##_2, W##kk##_3;
    DECLW(0) DECLW(1) DECLW(2) DECLW(3) DECLW(4) DECLW(5) DECLW(6) DECLW(7)
#undef DECLW
#define LOADW(kk) { const f32x4 w_ = *reinterpret_cast<const f32x4*>(      \
        &Wh[(size_t)(8 * ks + kk) * HID + 4 * cg]);                        \
        W##kk##_0 = w_.x; W##kk##_1 = w_.y;                                \
        W##kk##_2 = w_.z; W##kk##_3 = w_.w; }
    LOADW(0) LOADW(1) LOADW(2) LOADW(3) LOADW(4) LOADW(5) LOADW(6) LOADW(7)
#undef LOADW

    if (tid < 512) (&hbuf[0][0][0])[tid & 511] = 0.f;  // h0 = 0 (512 floats)
    __syncthreads();

    const int rf = tid >> 7;           // finalize row (only valid tid<256)
    const int cf = tid & 127;          // finalize column

    int cur = 0;
    for (int t = 0; t < SEQ; ++t) {
        // finalize waves issue xp gather early (hidden under the FMA block)
        float xp = 0.f;
        if (tid < 256)
            xp = EWx[(size_t)idx[rf][t] * HID + cf];

        const f32x4* h0 = (const f32x4*)&hbuf[cur][0][8 * ks];
        const f32x4* h1 = (const f32x4*)&hbuf[cur][1][8 * ks];

        float A0_0=0.f,A0_1=0.f,A0_2=0.f,A0_3=0.f;   // row 0, 4 cols
        float A1_0=0.f,A1_1=0.f,A1_2=0.f,A1_3=0.f;   // row 1, 4 cols

#define FMA8(kk, v0, v1)                                                   \
        A0_0=fmaf(v0,W##kk##_0,A0_0); A0_1=fmaf(v0,W##kk##_1,A0_1);        \
        A0_2=fmaf(v0,W##kk##_2,A0_2); A0_3=fmaf(v0,W##kk##_3,A0_3);        \
        A1_0=fmaf(v1,W##kk##_0,A1_0); A1_1=fmaf(v1,W##kk##_1,A1_1);        \
        A1_2=fmaf(v1,W##kk##_2,A1_2); A1_3=fmaf(v1,W##kk##_3,A1_3);

        { const f32x4 u0 = h0[0], u1 = h1[0];
          FMA8(0, u0.x, u1.x) FMA8(1, u0.y, u1.y)
          FMA8(2, u0.z, u1.z) FMA8(3, u0.w, u1.w) }
        { const f32x4 u0 = h0[1], u1 = h1[1];
          FMA8(4, u0.x, u1.x) FMA8(5, u0.y, u1.y)
          FMA8(6, u0.z, u1.z) FMA8(7, u0.w, u1.w) }
#undef FMA8

        // fold kql (lane bits 0,1): after this every lane holds the
        // k-quarter sum for its kqh; writers kql==0 store it.
#define FOLD(x) x += __shfl_xor(x, 1, 64); x += __shfl_xor(x, 2, 64);
        FOLD(A0_0) FOLD(A0_1) FOLD(A0_2) FOLD(A0_3)
        FOLD(A1_0) FOLD(A1_1) FOLD(A1_2) FOLD(A1_3)
#undef FOLD

        if (kql == 0) {
            f32x4 p;
            p.x=A0_0; p.y=A0_1; p.z=A0_2; p.w=A0_3;
            *reinterpret_cast<f32x4*>(&part[0][kqh][4 * cg]) = p;
            p.x=A1_0; p.y=A1_1; p.z=A1_2; p.w=A1_3;
            *reinterpret_cast<f32x4*>(&part[1][kqh][4 * cg]) = p;
        }
        __syncthreads();

        // finalize (waves 0-3, wave-uniform branch): 4-way reduce + tanh
        if (tid < 256) {
            const float s = xp + part[rf][0][cf] + part[rf][1][cf]
                               + part[rf][2][cf] + part[rf][3][cf];
            const float x  = fminf(fmaxf(s, -9.f), 9.f);
            const float e2 = __expf(2.f * x);
            hbuf[cur ^ 1][rf][cf] = __fdividef(e2 - 1.f, e2 + 1.f);
        }
        __syncthreads();
        cur ^= 1;
    }

    // head: out[b] = sigmoid(h . Wd + bd)
    if (tid < 128) {
        const int bb   = tid >> 6;
        const int lane = tid & 63;
        const float* hb = hbuf[cur][bb];
        float v = hb[lane] * Wd[lane] + hb[lane + 64] * Wd[lane + 64];
#pragma unroll
        for (int off = 32; off > 0; off >>= 1)
            v += __shfl_down(v, off, 64);
        if (lane == 0)
            out[b0 + bb] = 1.0f / (1.0f + expf(-(v + bd[0])));
    }
}

extern "C" void kernel_launch(void* const* d_in, const int* in_sizes, int n_in,
                              void* d_out, int out_size, void* d_ws, size_t ws_size,
                              hipStream_t stream)
{
    const int*   X  = (const int*)d_in[0];
    const float* E  = (const float*)d_in[1];
    const float* Wx = (const float*)d_in[2];
    const float* Wh = (const float*)d_in[3];
    const float* b  = (const float*)d_in[4];
    const float* Wd = (const float*)d_in[5];
    const float* bd = (const float*)d_in[6];
    float* out = (float*)d_out;
    float* EWx = (float*)d_ws;   // 30000*128*4 = 15.36 MB scratch

    ewx_kernel<<<dim3((VOCAB + 63) / 64), dim3(256), 0, stream>>>(E, Wx, b, EWx);
    rnn_kernel<<<dim3(BATCH / 2), dim3(512), 0, stream>>>(X, EWx, Wh, Wd, bd, out);
}

// Round 9
// 386.738 us; speedup vs baseline: 1.7505x; 1.7104x over previous
//
#include <hip/hip_runtime.h>
#include <math.h>

#define VOCAB 30000
#define EMB   100
#define HID   128
#define BATCH 1024
#define SEQ   512

typedef float f32x4 __attribute__((ext_vector_type(4)));

// Kernel A: EWx[v][j] = sum_e E[v][e]*Wx[e][j] + b[j]   (folds bias in)
__global__ __launch_bounds__(256) void ewx_kernel(
    const float* __restrict__ E, const float* __restrict__ Wx,
    const float* __restrict__ bias, float* __restrict__ EWx)
{
    __shared__ float Es[64][EMB];     // 25.6 KB
    __shared__ float Wxs[EMB][HID];   // 51.2 KB
    const int tid = threadIdx.x;
    const int v0 = blockIdx.x * 64;
    const int nv = min(64, VOCAB - v0);

    {
        const float4* s4 = (const float4*)Wx;
        float4* d4 = (float4*)(&Wxs[0][0]);
        for (int i = tid; i < (EMB * HID) / 4; i += 256) d4[i] = s4[i];
    }
    {
        const float* src = E + (size_t)v0 * EMB;
        float* dst = &Es[0][0];
        const int n  = nv * EMB;
        const int n4 = n >> 2;
        const float4* s4 = (const float4*)src;
        float4* d4 = (float4*)dst;
        for (int i = tid; i < n4; i += 256) d4[i] = s4[i];
        for (int i = (n4 << 2) + tid; i < n; i += 256) dst[i] = src[i];
    }
    __syncthreads();

    const int j  = tid & 127;
    const int vh = tid >> 7;
    float acc[32];
#pragma unroll
    for (int m = 0; m < 32; ++m) acc[m] = 0.f;

    for (int k4 = 0; k4 < EMB; k4 += 4) {
        const float w0 = Wxs[k4 + 0][j];
        const float w1 = Wxs[k4 + 1][j];
        const float w2 = Wxs[k4 + 2][j];
        const float w3 = Wxs[k4 + 3][j];
#pragma unroll
        for (int m = 0; m < 32; ++m) {
            const float4 e = *(const float4*)&Es[vh + 2 * m][k4];
            acc[m] = fmaf(e.x, w0, acc[m]);
            acc[m] = fmaf(e.y, w1, acc[m]);
            acc[m] = fmaf(e.z, w2, acc[m]);
            acc[m] = fmaf(e.w, w3, acc[m]);
        }
    }
    const float bj = bias[j];
#pragma unroll
    for (int m = 0; m < 32; ++m) {
        const int v = vh + 2 * m;
        if (v < nv)
            EWx[(size_t)(v0 + v) * HID + j] = acc[m] + bj;
    }
}

// Kernel B: wave-closed recurrence. 256 threads, 2 batch rows/block,
// grid 512 = 2 blocks/CU (256-thr blocks: r7/r8 proved 512-thr barriers
// cost ~2x). waves_per_eu(2,2): r6-proven weight residency config.
//
// Wave w (=tid>>6) k-slice [32w,32w+32) == the columns it finalizes, so
// h is WAVE-LOCAL: finalize writes h[row][32w+jc], next step's FMA reads
// h[*][32w+16kh..+16) — same wave, in-order DS pipe, NO barrier for h.
// ONE barrier/step (k-partial exchange), part[] double-buffered.
// Lane = (kh = (tid>>5)&1, jc = tid&31): weights Wh[32w+16kh+kk][4jc+c]
// (64 named scalars), FMAs partials for all 128 cols x 2 rows over its
// 16 k's = 128 FMA/thread. Fold kh via shfl_xor(32); lane kh writes row
// kh's b128 partial; after barrier lane (kh,jc) finalizes (row kh, col
// 32w+jc): 4 stride-1 b32 part reads + xp + tanh.
// xp (EWx gather, ~40% HBM-miss ~900cyc: FETCH 99MB/step evidence) is
// prefetched 4 STEPS AHEAD in 4 rotating named regs (t-loop unrolled x4)
// -> off the critical path.
__global__ __launch_bounds__(256)
__attribute__((amdgpu_waves_per_eu(2, 2)))
void rnn_kernel(
    const int* __restrict__ X, const float* __restrict__ EWx,
    const float* __restrict__ Wh, const float* __restrict__ Wd,
    const float* __restrict__ bd, float* __restrict__ out)
{
    __shared__ __align__(16) float hbuf[2][HID];        // [row][col], 1 KB
    __shared__ __align__(16) float part[2][2][4][HID];  // [buf][row][wave][col], 4 KB
    __shared__ int idx[2][SEQ];                         // 4 KB

    const int tid = threadIdx.x;
    const int w   = tid >> 6;          // wave 0..3: k-slice & col-slice owner
    const int kh  = (tid >> 5) & 1;    // k-half within wave; finalize row
    const int jc  = tid & 31;
    const int b0  = blockIdx.x * 2;

    for (int i = tid; i < 2 * SEQ; i += 256)
        idx[i >> 9][i & 511] = X[(size_t)(b0 + (i >> 9)) * SEQ + (i & 511)];

    // 64 weights in named scalars: W{kk}_{c} = Wh[32w+16kh+kk][4jc+c]
    const float* wb = Wh + (size_t)(32 * w + 16 * kh) * HID + 4 * jc;
#define DECLW(kk) float W##kk##_0, W##kk##_1, W##kk##_2, W##kk##_3;
    DECLW(0)  DECLW(1)  DECLW(2)  DECLW(3)
    DECLW(4)  DECLW(5)  DECLW(6)  DECLW(7)
    DECLW(8)  DECLW(9)  DECLW(10) DECLW(11)
    DECLW(12) DECLW(13) DECLW(14) DECLW(15)
#undef DECLW
#define LOADW(kk) { const f32x4 w_ = *reinterpret_cast<const f32x4*>(wb + (kk) * HID); \
        W##kk##_0 = w_.x; W##kk##_1 = w_.y; W##kk##_2 = w_.z; W##kk##_3 = w_.w; }
    LOADW(0)  LOADW(1)  LOADW(2)  LOADW(3)
    LOADW(4)  LOADW(5)  LOADW(6)  LOADW(7)
    LOADW(8)  LOADW(9)  LOADW(10) LOADW(11)
    LOADW(12) LOADW(13) LOADW(14) LOADW(15)
#undef LOADW

    (&hbuf[0][0])[tid] = 0.f;          // h0 = 0 (256 floats total)
    __syncthreads();

    const int cf = 32 * w + jc;        // finalize column (row = kh)
    const f32x4* h0r = (const f32x4*)&hbuf[0][32 * w + 16 * kh];
    const f32x4* h1r = (const f32x4*)&hbuf[1][32 * w + 16 * kh];

    // xp prologue: 4-deep prefetch
    float xp0 = EWx[(size_t)idx[kh][0] * HID + cf];
    float xp1 = EWx[(size_t)idx[kh][1] * HID + cf];
    float xp2 = EWx[(size_t)idx[kh][2] * HID + cf];
    float xp3 = EWx[(size_t)idx[kh][3] * HID + cf];

#define FMAK(kk, hv0, hv1)                                                  \
        A00 = fmaf(hv0, W##kk##_0, A00); A01 = fmaf(hv0, W##kk##_1, A01);   \
        A02 = fmaf(hv0, W##kk##_2, A02); A03 = fmaf(hv0, W##kk##_3, A03);   \
        A10 = fmaf(hv1, W##kk##_0, A10); A11 = fmaf(hv1, W##kk##_1, A11);   \
        A12 = fmaf(hv1, W##kk##_2, A12); A13 = fmaf(hv1, W##kk##_3, A13);

#define BODY(T, P, XP) {                                                    \
        const f32x4 u00 = h0r[0], u01 = h0r[1], u02 = h0r[2], u03 = h0r[3]; \
        const f32x4 u10 = h1r[0], u11 = h1r[1], u12 = h1r[2], u13 = h1r[3]; \
        float A00=0.f,A01=0.f,A02=0.f,A03=0.f;                              \
        float A10=0.f,A11=0.f,A12=0.f,A13=0.f;                              \
        FMAK(0,  u00.x, u10.x) FMAK(1,  u00.y, u10.y)                       \
        FMAK(2,  u00.z, u10.z) FMAK(3,  u00.w, u10.w)                       \
        FMAK(4,  u01.x, u11.x) FMAK(5,  u01.y, u11.y)                       \
        FMAK(6,  u01.z, u11.z) FMAK(7,  u01.w, u11.w)                       \
        FMAK(8,  u02.x, u12.x) FMAK(9,  u02.y, u12.y)                       \
        FMAK(10, u02.z, u12.z) FMAK(11, u02.w, u12.w)                       \
        FMAK(12, u03.x, u13.x) FMAK(13, u03.y, u13.y)                       \
        FMAK(14, u03.z, u13.z) FMAK(15, u03.w, u13.w)                       \
        /* fold k-halves across lane^32: both halves get full-k sums */     \
        A00 += __shfl_xor(A00, 32); A01 += __shfl_xor(A01, 32);             \
        A02 += __shfl_xor(A02, 32); A03 += __shfl_xor(A03, 32);             \
        A10 += __shfl_xor(A10, 32); A11 += __shfl_xor(A11, 32);             \
        A12 += __shfl_xor(A12, 32); A13 += __shfl_xor(A13, 32);             \
        /* lane half kh stores row kh's partial (b128, conflict-free) */    \
        f32x4 pw;                                                           \
        pw.x = kh ? A10 : A00; pw.y = kh ? A11 : A01;                       \
        pw.z = kh ? A12 : A02; pw.w = kh ? A13 : A03;                       \
        *reinterpret_cast<f32x4*>(&part[P][kh][w][4 * jc]) = pw;            \
        __syncthreads();                                                    \
        /* finalize (row kh, col cf): 4-way reduce + xp + tanh */           \
        const float s = XP + part[P][kh][0][cf] + part[P][kh][1][cf]        \
                           + part[P][kh][2][cf] + part[P][kh][3][cf];       \
        const float xv = fminf(fmaxf(s, -9.f), 9.f);                        \
        const float e2 = __expf(2.f * xv);                                  \
        hbuf[kh][cf] = __fdividef(e2 - 1.f, e2 + 1.f);                      \
        /* refill prefetch slot for step T+4 */                             \
        const int tt = (T) + 4 < SEQ ? (T) + 4 : SEQ - 1;                   \
        XP = EWx[(size_t)idx[kh][tt] * HID + cf];                           \
    }

#pragma unroll 1
    for (int t = 0; t < SEQ; t += 4) {
        BODY(t + 0, 0, xp0)
        BODY(t + 1, 1, xp1)
        BODY(t + 2, 0, xp2)
        BODY(t + 3, 1, xp3)
    }
#undef BODY
#undef FMAK

    __syncthreads();

    // head: out[b] = sigmoid(h . Wd + bd)
    if (tid < 128) {
        const int bb   = tid >> 6;
        const int lane = tid & 63;
        const float* hb = hbuf[bb];
        float v = hb[lane] * Wd[lane] + hb[lane + 64] * Wd[lane + 64];
#pragma unroll
        for (int off = 32; off > 0; off >>= 1)
            v += __shfl_down(v, off, 64);
        if (lane == 0)
            out[b0 + bb] = 1.0f / (1.0f + expf(-(v + bd[0])));
    }
}

extern "C" void kernel_launch(void* const* d_in, const int* in_sizes, int n_in,
                              void* d_out, int out_size, void* d_ws, size_t ws_size,
                              hipStream_t stream)
{
    const int*   X  = (const int*)d_in[0];
    const float* E  = (const float*)d_in[1];
    const float* Wx = (const float*)d_in[2];
    const float* Wh = (const float*)d_in[3];
    const float* b  = (const float*)d_in[4];
    const float* Wd = (const float*)d_in[5];
    const float* bd = (const float*)d_in[6];
    float* out = (float*)d_out;
    float* EWx = (float*)d_ws;   // 30000*128*4 = 15.36 MB scratch

    ewx_kernel<<<dim3((VOCAB + 63) / 64), dim3(256), 0, stream>>>(E, Wx, b, EWx);
    rnn_kernel<<<dim3(BATCH / 2), dim3(256), 0, stream>>>(X, EWx, Wh, Wd, bd, out);
}